// Round 3
// baseline (372.541 us; speedup 1.0000x reference)
//
#include <hip/hip_runtime.h>
#include <hip/hip_bf16.h>

#define BATCH 8192
#define NCH 8
#define CIN 512
#define COUT 512
#define NF 4096  /* in/out features */

typedef __attribute__((ext_vector_type(8))) __bf16 bf16x8;
typedef __attribute__((ext_vector_type(4))) float f32x4;

__device__ __forceinline__ void async_load16(const void* g, void* l) {
    __builtin_amdgcn_global_load_lds((const __attribute__((address_space(1))) void*)g,
                                     (__attribute__((address_space(3))) void*)l, 16, 0, 0);
}

__device__ __forceinline__ bf16x8 cvt8(const float4 a, const float4 b) {
    bf16x8 p;
    p[0] = (__bf16)a.x; p[1] = (__bf16)a.y; p[2] = (__bf16)a.z; p[3] = (__bf16)a.w;
    p[4] = (__bf16)b.x; p[5] = (__bf16)b.y; p[6] = (__bf16)b.z; p[7] = (__bf16)b.w;
    return p;
}

// ---------------- kernel 1: |x| reduce per chunk + fused top-2 (last block) ----------------
// grid (256, 8), block 256. Block (bx, c): rows bx*32..+32 of chunk c.
__global__ __launch_bounds__(256) void act_kernel(const float* __restrict__ x,
                                                  float* __restrict__ sums,
                                                  unsigned int* __restrict__ counter,
                                                  float* __restrict__ out_act,
                                                  int* __restrict__ idx_out) {
    const int c = blockIdx.y;
    const int bx = blockIdx.x;
    const int t = threadIdx.x;
    const int wv = t >> 6;               // wave 0..3
    const int col = (t & 63) * 8;        // 0..504
    const size_t rbase = (size_t)bx * 32;
    float s = 0.f;
#pragma unroll
    for (int p = 0; p < 8; ++p) {
        const size_t r = rbase + p * 4 + wv;
        const float* src = x + r * NF + c * CIN + col;
        const float4 a0 = *(const float4*)(src);
        const float4 a1 = *(const float4*)(src + 4);
        s += fabsf(a0.x) + fabsf(a0.y) + fabsf(a0.z) + fabsf(a0.w)
           + fabsf(a1.x) + fabsf(a1.y) + fabsf(a1.z) + fabsf(a1.w);
    }
#pragma unroll
    for (int off = 32; off > 0; off >>= 1) s += __shfl_down(s, off, 64);
    __shared__ float red[4];
    const int lane = t & 63;
    if (lane == 0) red[wv] = s;
    __syncthreads();
    if (t == 0) {
        atomicAdd(&sums[c], red[0] + red[1] + red[2] + red[3]);
        __threadfence();
        const unsigned int old = atomicAdd(counter, 1u);
        if (old == 256u * NCH - 1u) {   // last block: all sums complete
            __threadfence();
            const float scale = 1.0f / ((float)BATCH * (float)CIN);
            float a[NCH];
            for (int i = 0; i < NCH; ++i) {
                a[i] = atomicAdd(&sums[i], 0.0f) * scale;  // device-coherent read
                out_act[i] = a[i];
            }
            int i0 = 0;
            for (int i = 1; i < NCH; ++i) if (a[i] > a[i0]) i0 = i;   // tie -> lower idx
            int i1 = (i0 == 0) ? 1 : 0;
            for (int i = 0; i < NCH; ++i) if (i != i0 && a[i] > a[i1]) i1 = i;
            idx_out[0] = i0; idx_out[1] = i1;
        }
    }
}

// ---------------- kernel 2: convert ONLY the 2 selected chunks (x and W) to bf16 ----------------
// grid (264, 2), block 256. bx<256: x rows; bx>=256: W slice.
__global__ __launch_bounds__(256) void cvt_kernel(const float* __restrict__ x,
                                                  const float* __restrict__ W,
                                                  const int* __restrict__ idx,
                                                  __bf16* __restrict__ xc,
                                                  __bf16* __restrict__ wc) {
    const int z = blockIdx.y;            // compact chunk id 0/1
    const int c = idx[z];
    const int bx = blockIdx.x;
    const int t = threadIdx.x;

    if (bx >= 256) {
        const int q = bx - 256;          // 0..7
        const float* src = W + (size_t)c * (COUT * CIN) + q * 32768;
        __bf16* dst = wc + (size_t)z * (COUT * CIN) + q * 32768;
#pragma unroll
        for (int p = 0; p < 16; ++p) {
            const int off = p * 2048 + t * 8;
            const float4 a0 = *(const float4*)(src + off);
            const float4 a1 = *(const float4*)(src + off + 4);
            *(bf16x8*)(dst + off) = cvt8(a0, a1);
        }
        return;
    }

    const int wv = t >> 6;
    const int col = (t & 63) * 8;
    const size_t rbase = (size_t)bx * 32;
    __bf16* dst = xc + (size_t)z * BATCH * CIN;
#pragma unroll
    for (int p = 0; p < 8; ++p) {
        const size_t r = rbase + p * 4 + wv;
        const float* src = x + r * NF + c * CIN + col;
        const float4 a0 = *(const float4*)(src);
        const float4 a1 = *(const float4*)(src + 4);
        *(bf16x8*)(dst + r * CIN + col) = cvt8(a0, a1);
    }
}

// ---------------- kernel 3: bf16 GEMM on selected chunks, zeros elsewhere ----------------
// grid (64, 4, 8), block 256 (4 waves). Tile 128x128, K=512 in BK=32 steps.
// m97 structure: global_load_lds dwordx4 staging, unpadded [row][32] LDS tiles.
__global__ __launch_bounds__(256) void gemm_kernel(const __bf16* __restrict__ xc,
                                                   const __bf16* __restrict__ wc,
                                                   const float* __restrict__ bias,
                                                   const int* __restrict__ idx,
                                                   float* __restrict__ out) {
    const int c = blockIdx.z;
    const int t = threadIdx.x;
    const size_t obase = (size_t)(blockIdx.x * 128) * NF + c * COUT + blockIdx.y * 128;
    const int i0 = idx[0], i1 = idx[1];

    if (c != i0 && c != i1) {
        const float4 z = make_float4(0.f, 0.f, 0.f, 0.f);
        const int rq = t >> 5;             // 0..7
        const int cq = (t & 31) << 2;      // 0..124 step 4
#pragma unroll
        for (int p = 0; p < 16; ++p)
            *(float4*)(out + obase + (size_t)(p * 8 + rq) * NF + cq) = z;
        return;
    }
    const int kz = (c == i0) ? 0 : 1;      // compact chunk id

    __shared__ __bf16 Xs[128 * 32];   // [row][32], UNPADDED (global_load_lds layout)
    __shared__ __bf16 Wsh[128 * 32];

    const int lane = t & 63, w = t >> 6;
    const int wm = (w >> 1) * 64, wn = (w & 1) * 64;   // wave 64x64 sub-tile
    const int lr = lane & 15, lq = lane >> 4;

    // staging: wave w covers rows [w*32, w*32+32) in two 16-row issues
    const int srow = lane >> 2;          // 0..15
    const int skcol = (lane & 3) * 8;    // bf16 k-col within BK
    const __bf16* xg = xc + (size_t)kz * BATCH * CIN
                     + (size_t)(blockIdx.x * 128 + w * 32 + srow) * CIN + skcol;
    const __bf16* wg = wc + (size_t)kz * COUT * CIN
                     + (size_t)(blockIdx.y * 128 + w * 32 + srow) * CIN + skcol;
    __bf16* xls = &Xs[(w * 32) * 32];
    __bf16* wls = &Wsh[(w * 32) * 32];

    f32x4 acc[4][4];
#pragma unroll
    for (int i = 0; i < 4; ++i)
#pragma unroll
        for (int j = 0; j < 4; ++j) acc[i][j] = (f32x4){0.f, 0.f, 0.f, 0.f};

    for (int kk = 0; kk < CIN; kk += 32) {
        async_load16(xg + kk, xls);
        async_load16(xg + kk + (size_t)16 * CIN, xls + 16 * 32);
        async_load16(wg + kk, wls);
        async_load16(wg + kk + (size_t)16 * CIN, wls + 16 * 32);
        __syncthreads();   // drains vmcnt(0): LDS tiles complete

        bf16x8 av[4], bv[4];
#pragma unroll
        for (int mt = 0; mt < 4; ++mt) av[mt] = *(const bf16x8*)&Xs[(wm + mt * 16 + lr) * 32 + lq * 8];
#pragma unroll
        for (int nt = 0; nt < 4; ++nt) bv[nt] = *(const bf16x8*)&Wsh[(wn + nt * 16 + lr) * 32 + lq * 8];
#pragma unroll
        for (int mt = 0; mt < 4; ++mt)
#pragma unroll
            for (int nt = 0; nt < 4; ++nt)
                acc[mt][nt] = __builtin_amdgcn_mfma_f32_16x16x32_bf16(av[mt], bv[nt], acc[mt][nt], 0, 0, 0);
        __syncthreads();
    }

    // ---- epilogue: + bias, store fp32 ----
    float bvv[4];
#pragma unroll
    for (int nt = 0; nt < 4; ++nt)
        bvv[nt] = bias[c * COUT + blockIdx.y * 128 + wn + nt * 16 + lr];
#pragma unroll
    for (int mt = 0; mt < 4; ++mt)
#pragma unroll
        for (int nt = 0; nt < 4; ++nt)
#pragma unroll
            for (int r = 0; r < 4; ++r) {
                const int row = wm + mt * 16 + lq * 4 + r;   // C/D: row = quad*4 + reg
                const int col = wn + nt * 16 + lr;           // C/D: col = lane&15
                out[obase + (size_t)row * NF + col] = acc[mt][nt][r] + bvv[nt];
            }
}

extern "C" void kernel_launch(void* const* d_in, const int* in_sizes, int n_in,
                              void* d_out, int out_size, void* d_ws, size_t ws_size,
                              hipStream_t stream) {
    const float* x = (const float*)d_in[0];
    const float* W = (const float*)d_in[1];
    const float* b = (const float*)d_in[2];
    float* out = (float*)d_out;

    // ws layout: [0,32) sums, [32,36) counter, [40,48) idx, [256,...) xc (16 MiB), wc (1 MiB)
    float* sums = (float*)d_ws;
    unsigned int* counter = (unsigned int*)((char*)d_ws + 32);
    int* idx = (int*)((char*)d_ws + 40);
    __bf16* xc = (__bf16*)((char*)d_ws + 256);
    __bf16* wc = (__bf16*)((char*)d_ws + 256 + (size_t)2 * BATCH * CIN * 2);

    hipMemsetAsync(d_ws, 0, 64, stream);
    act_kernel<<<dim3(256, NCH), 256, 0, stream>>>(x, sums, counter,
                                                   out + (size_t)BATCH * NF, idx);
    cvt_kernel<<<dim3(264, 2), 256, 0, stream>>>(x, W, idx, xc, wc);
    gemm_kernel<<<dim3(64, 4, NCH), 256, 0, stream>>>(xc, wc, b, idx, out);
}

// Round 4
// 271.812 us; speedup vs baseline: 1.3706x; 1.3706x over previous
//
#include <hip/hip_runtime.h>
#include <hip/hip_bf16.h>

#define BATCH 8192
#define NCH 8
#define CIN 512
#define COUT 512
#define NF 4096  /* in/out features */

typedef __attribute__((ext_vector_type(8))) __bf16 bf16x8;
typedef __attribute__((ext_vector_type(4))) float f32x4;

__device__ __forceinline__ void async_load16(const void* g, void* l) {
    __builtin_amdgcn_global_load_lds((const __attribute__((address_space(1))) void*)g,
                                     (__attribute__((address_space(3))) void*)l, 16, 0, 0);
}

__device__ __forceinline__ bf16x8 cvt8(const float4 a, const float4 b) {
    bf16x8 p;
    p[0] = (__bf16)a.x; p[1] = (__bf16)a.y; p[2] = (__bf16)a.z; p[3] = (__bf16)a.w;
    p[4] = (__bf16)b.x; p[5] = (__bf16)b.y; p[6] = (__bf16)b.z; p[7] = (__bf16)b.w;
    return p;
}

// ---------------- kernel 1: |x| reduce per chunk ----------------
// grid (256, 8), block 256. Block (bx, c): rows bx*32..+32 of chunk c.
// NOTE: no single-address block-done counter here — 2048 same-address
// device atomics serialized at ~80 ns each (165 us, round-3 regression).
__global__ __launch_bounds__(256) void act_kernel(const float* __restrict__ x,
                                                  float* __restrict__ sums) {
    const int c = blockIdx.y;
    const int bx = blockIdx.x;
    const int t = threadIdx.x;
    const int wv = t >> 6;               // wave 0..3
    const int col = (t & 63) * 8;        // 0..504
    const size_t rbase = (size_t)bx * 32;
    float s = 0.f;
#pragma unroll
    for (int p = 0; p < 8; ++p) {
        const size_t r = rbase + p * 4 + wv;
        const float* src = x + r * NF + c * CIN + col;
        const float4 a0 = *(const float4*)(src);
        const float4 a1 = *(const float4*)(src + 4);
        s += fabsf(a0.x) + fabsf(a0.y) + fabsf(a0.z) + fabsf(a0.w)
           + fabsf(a1.x) + fabsf(a1.y) + fabsf(a1.z) + fabsf(a1.w);
    }
#pragma unroll
    for (int off = 32; off > 0; off >>= 1) s += __shfl_down(s, off, 64);
    __shared__ float red[4];
    const int lane = t & 63;
    if (lane == 0) red[wv] = s;
    __syncthreads();
    if (t == 0) atomicAdd(&sums[c], red[0] + red[1] + red[2] + red[3]);
}

// ---------------- kernel 2: activities + top-2 ----------------
__global__ void topk_kernel(const float* __restrict__ sums,
                            float* __restrict__ out_act,
                            int* __restrict__ idx_out) {
    if (threadIdx.x == 0) {
        const float scale = 1.0f / ((float)BATCH * (float)CIN);
        float a[NCH];
        for (int i = 0; i < NCH; ++i) { a[i] = sums[i] * scale; out_act[i] = a[i]; }
        int i0 = 0;
        for (int i = 1; i < NCH; ++i) if (a[i] > a[i0]) i0 = i;   // tie -> lower idx
        int i1 = (i0 == 0) ? 1 : 0;
        for (int i = 0; i < NCH; ++i) if (i != i0 && a[i] > a[i1]) i1 = i;
        idx_out[0] = i0; idx_out[1] = i1;
    }
}

// ---------------- kernel 3: convert ONLY the 2 selected chunks (x and W) to bf16 ----------------
// grid (264, 2), block 256. bx<256: x rows; bx>=256: W slice.
__global__ __launch_bounds__(256) void cvt_kernel(const float* __restrict__ x,
                                                  const float* __restrict__ W,
                                                  const int* __restrict__ idx,
                                                  __bf16* __restrict__ xc,
                                                  __bf16* __restrict__ wc) {
    const int z = blockIdx.y;            // compact chunk id 0/1
    const int c = idx[z];
    const int bx = blockIdx.x;
    const int t = threadIdx.x;

    if (bx >= 256) {
        const int q = bx - 256;          // 0..7
        const float* src = W + (size_t)c * (COUT * CIN) + q * 32768;
        __bf16* dst = wc + (size_t)z * (COUT * CIN) + q * 32768;
#pragma unroll
        for (int p = 0; p < 16; ++p) {
            const int off = p * 2048 + t * 8;
            const float4 a0 = *(const float4*)(src + off);
            const float4 a1 = *(const float4*)(src + off + 4);
            *(bf16x8*)(dst + off) = cvt8(a0, a1);
        }
        return;
    }

    const int wv = t >> 6;
    const int col = (t & 63) * 8;
    const size_t rbase = (size_t)bx * 32;
    __bf16* dst = xc + (size_t)z * BATCH * CIN;
#pragma unroll
    for (int p = 0; p < 8; ++p) {
        const size_t r = rbase + p * 4 + wv;
        const float* src = x + r * NF + c * CIN + col;
        const float4 a0 = *(const float4*)(src);
        const float4 a1 = *(const float4*)(src + 4);
        *(bf16x8*)(dst + r * CIN + col) = cvt8(a0, a1);
    }
}

// ---------------- kernel 4: bf16 GEMM on selected chunks, zeros elsewhere ----------------
// grid (64, 4, 8), block 256 (4 waves). Tile 128x128, K=512 in BK=32 steps.
// m97 structure: global_load_lds dwordx4 staging, unpadded [row][32] LDS tiles.
__global__ __launch_bounds__(256) void gemm_kernel(const __bf16* __restrict__ xc,
                                                   const __bf16* __restrict__ wc,
                                                   const float* __restrict__ bias,
                                                   const int* __restrict__ idx,
                                                   float* __restrict__ out) {
    const int c = blockIdx.z;
    const int t = threadIdx.x;
    const size_t obase = (size_t)(blockIdx.x * 128) * NF + c * COUT + blockIdx.y * 128;
    const int i0 = idx[0], i1 = idx[1];

    if (c != i0 && c != i1) {
        const float4 z = make_float4(0.f, 0.f, 0.f, 0.f);
        const int rq = t >> 5;             // 0..7
        const int cq = (t & 31) << 2;      // 0..124 step 4
#pragma unroll
        for (int p = 0; p < 16; ++p)
            *(float4*)(out + obase + (size_t)(p * 8 + rq) * NF + cq) = z;
        return;
    }
    const int kz = (c == i0) ? 0 : 1;      // compact chunk id

    __shared__ __bf16 Xs[128 * 32];   // [row][32], UNPADDED (global_load_lds layout)
    __shared__ __bf16 Wsh[128 * 32];

    const int lane = t & 63, w = t >> 6;
    const int wm = (w >> 1) * 64, wn = (w & 1) * 64;   // wave 64x64 sub-tile
    const int lr = lane & 15, lq = lane >> 4;

    // staging: wave w covers rows [w*32, w*32+32) in two 16-row issues
    const int srow = lane >> 2;          // 0..15
    const int skcol = (lane & 3) * 8;    // bf16 k-col within BK
    const __bf16* xg = xc + (size_t)kz * BATCH * CIN
                     + (size_t)(blockIdx.x * 128 + w * 32 + srow) * CIN + skcol;
    const __bf16* wg = wc + (size_t)kz * COUT * CIN
                     + (size_t)(blockIdx.y * 128 + w * 32 + srow) * CIN + skcol;
    __bf16* xls = &Xs[(w * 32) * 32];
    __bf16* wls = &Wsh[(w * 32) * 32];

    f32x4 acc[4][4];
#pragma unroll
    for (int i = 0; i < 4; ++i)
#pragma unroll
        for (int j = 0; j < 4; ++j) acc[i][j] = (f32x4){0.f, 0.f, 0.f, 0.f};

    for (int kk = 0; kk < CIN; kk += 32) {
        async_load16(xg + kk, xls);
        async_load16(xg + kk + (size_t)16 * CIN, xls + 16 * 32);
        async_load16(wg + kk, wls);
        async_load16(wg + kk + (size_t)16 * CIN, wls + 16 * 32);
        __syncthreads();   // drains vmcnt(0): LDS tiles complete

        bf16x8 av[4], bv[4];
#pragma unroll
        for (int mt = 0; mt < 4; ++mt) av[mt] = *(const bf16x8*)&Xs[(wm + mt * 16 + lr) * 32 + lq * 8];
#pragma unroll
        for (int nt = 0; nt < 4; ++nt) bv[nt] = *(const bf16x8*)&Wsh[(wn + nt * 16 + lr) * 32 + lq * 8];
#pragma unroll
        for (int mt = 0; mt < 4; ++mt)
#pragma unroll
            for (int nt = 0; nt < 4; ++nt)
                acc[mt][nt] = __builtin_amdgcn_mfma_f32_16x16x32_bf16(av[mt], bv[nt], acc[mt][nt], 0, 0, 0);
        __syncthreads();
    }

    // ---- epilogue: + bias, store fp32 ----
    float bvv[4];
#pragma unroll
    for (int nt = 0; nt < 4; ++nt)
        bvv[nt] = bias[c * COUT + blockIdx.y * 128 + wn + nt * 16 + lr];
#pragma unroll
    for (int mt = 0; mt < 4; ++mt)
#pragma unroll
        for (int nt = 0; nt < 4; ++nt)
#pragma unroll
            for (int r = 0; r < 4; ++r) {
                const int row = wm + mt * 16 + lq * 4 + r;   // C/D: row = quad*4 + reg
                const int col = wn + nt * 16 + lr;           // C/D: col = lane&15
                out[obase + (size_t)row * NF + col] = acc[mt][nt][r] + bvv[nt];
            }
}

extern "C" void kernel_launch(void* const* d_in, const int* in_sizes, int n_in,
                              void* d_out, int out_size, void* d_ws, size_t ws_size,
                              hipStream_t stream) {
    const float* x = (const float*)d_in[0];
    const float* W = (const float*)d_in[1];
    const float* b = (const float*)d_in[2];
    float* out = (float*)d_out;

    // ws layout: [0,32) sums, [40,48) idx, [256,...) xc (16 MiB), wc (1 MiB)
    float* sums = (float*)d_ws;
    int* idx = (int*)((char*)d_ws + 40);
    __bf16* xc = (__bf16*)((char*)d_ws + 256);
    __bf16* wc = (__bf16*)((char*)d_ws + 256 + (size_t)2 * BATCH * CIN * 2);

    hipMemsetAsync(d_ws, 0, 64, stream);
    act_kernel<<<dim3(256, NCH), 256, 0, stream>>>(x, sums);
    topk_kernel<<<1, 64, 0, stream>>>(sums, out + (size_t)BATCH * NF, idx);
    cvt_kernel<<<dim3(264, 2), 256, 0, stream>>>(x, W, idx, xc, wc);
    gemm_kernel<<<dim3(64, 4, NCH), 256, 0, stream>>>(xc, wc, b, idx, out);
}

// Round 5
// 271.533 us; speedup vs baseline: 1.3720x; 1.0010x over previous
//
#include <hip/hip_runtime.h>
#include <hip/hip_bf16.h>

#define BATCH 8192
#define NCH 8
#define CIN 512
#define COUT 512
#define NF 4096  /* in/out features */

typedef __attribute__((ext_vector_type(8))) __bf16 bf16x8;
typedef __attribute__((ext_vector_type(4))) float f32x4;

__device__ __forceinline__ void async_load16(const void* g, void* l) {
    __builtin_amdgcn_global_load_lds((const __attribute__((address_space(1))) void*)g,
                                     (__attribute__((address_space(3))) void*)l, 16, 0, 0);
}

__device__ __forceinline__ bf16x8 cvt8(const float4 a, const float4 b) {
    bf16x8 p;
    p[0] = (__bf16)a.x; p[1] = (__bf16)a.y; p[2] = (__bf16)a.z; p[3] = (__bf16)a.w;
    p[4] = (__bf16)b.x; p[5] = (__bf16)b.y; p[6] = (__bf16)b.z; p[7] = (__bf16)b.w;
    return p;
}

// Per-block recompute of chunk sums + top-2 from the 2048-entry partials array.
// Deterministic (fixed reduction order) -> every block agrees. ~8 L2-hot
// loads/thread + shfl tree; no single-address atomics (round-3 lesson).
__device__ __forceinline__ void recompute_top2(const float* __restrict__ partials,
                                               float* asums /* LDS[8] */,
                                               int& i0, int& i1) {
    const int t = threadIdx.x;
    const int c = t >> 5;        // chunk 0..7
    const int j = t & 31;
    float p = 0.f;
#pragma unroll
    for (int k = 0; k < 8; ++k) p += partials[c * 256 + j * 8 + k];
#pragma unroll
    for (int off = 16; off > 0; off >>= 1) p += __shfl_down(p, off, 32);
    if (j == 0) asums[c] = p;
    __syncthreads();
    float a[NCH];
#pragma unroll
    for (int i = 0; i < NCH; ++i) a[i] = asums[i];
    i0 = 0;
#pragma unroll
    for (int i = 1; i < NCH; ++i) if (a[i] > a[i0]) i0 = i;   // tie -> lower idx
    i1 = (i0 == 0) ? 1 : 0;
#pragma unroll
    for (int i = 0; i < NCH; ++i) if (i != i0 && a[i] > a[i1]) i1 = i;
}

// ---------------- kernel 1: |x| reduce per chunk -> partials (no atomics) ----------------
// grid (256, 8), block 256. Block (bx, c): rows bx*32..+32 of chunk c.
__global__ __launch_bounds__(256) void act_kernel(const float* __restrict__ x,
                                                  float* __restrict__ partials) {
    const int c = blockIdx.y;
    const int bx = blockIdx.x;
    const int t = threadIdx.x;
    const int wv = t >> 6;               // wave 0..3
    const int col = (t & 63) * 8;        // 0..504
    const size_t rbase = (size_t)bx * 32;
    float s = 0.f;
#pragma unroll
    for (int p = 0; p < 8; ++p) {
        const size_t r = rbase + p * 4 + wv;
        const float* src = x + r * NF + c * CIN + col;
        const float4 a0 = *(const float4*)(src);
        const float4 a1 = *(const float4*)(src + 4);
        s += fabsf(a0.x) + fabsf(a0.y) + fabsf(a0.z) + fabsf(a0.w)
           + fabsf(a1.x) + fabsf(a1.y) + fabsf(a1.z) + fabsf(a1.w);
    }
#pragma unroll
    for (int off = 32; off > 0; off >>= 1) s += __shfl_down(s, off, 64);
    __shared__ float red[4];
    const int lane = t & 63;
    if (lane == 0) red[wv] = s;
    __syncthreads();
    if (t == 0) partials[c * 256 + bx] = red[0] + red[1] + red[2] + red[3];
}

// ---------------- kernel 2: convert the 2 selected chunks (x, W) to bf16 ----------------
// grid (264, 2), block 256. bx<256: x rows; bx>=256: W slice. Block (0,0) also
// writes the activities output.
__global__ __launch_bounds__(256) void cvt_kernel(const float* __restrict__ x,
                                                  const float* __restrict__ W,
                                                  const float* __restrict__ partials,
                                                  __bf16* __restrict__ xc,
                                                  __bf16* __restrict__ wc,
                                                  float* __restrict__ out_act) {
    __shared__ float asums[NCH];
    int i0, i1;
    recompute_top2(partials, asums, i0, i1);

    const int z = blockIdx.y;            // compact chunk id 0/1
    const int c = (z == 0) ? i0 : i1;
    const int bx = blockIdx.x;
    const int t = threadIdx.x;

    if (bx == 0 && z == 0 && t < NCH)
        out_act[t] = asums[t] * (1.0f / ((float)BATCH * (float)CIN));

    if (bx >= 256) {
        const int q = bx - 256;          // 0..7
        const float* src = W + (size_t)c * (COUT * CIN) + q * 32768;
        __bf16* dst = wc + (size_t)z * (COUT * CIN) + q * 32768;
#pragma unroll
        for (int p = 0; p < 16; ++p) {
            const int off = p * 2048 + t * 8;
            const float4 a0 = *(const float4*)(src + off);
            const float4 a1 = *(const float4*)(src + off + 4);
            *(bf16x8*)(dst + off) = cvt8(a0, a1);
        }
        return;
    }

    const int wv = t >> 6;
    const int col = (t & 63) * 8;
    const size_t rbase = (size_t)bx * 32;
    __bf16* dst = xc + (size_t)z * BATCH * CIN;
#pragma unroll
    for (int p = 0; p < 8; ++p) {
        const size_t r = rbase + p * 4 + wv;
        const float* src = x + r * NF + c * CIN + col;
        const float4 a0 = *(const float4*)(src);
        const float4 a1 = *(const float4*)(src + 4);
        *(bf16x8*)(dst + r * CIN + col) = cvt8(a0, a1);
    }
}

// ---------------- kernel 3: bf16 GEMM on selected chunks, zeros elsewhere ----------------
// grid (64, 4, 8), block 256 (4 waves). Tile 128x128, K=512 in BK=32 steps.
// m97 structure: global_load_lds dwordx4 staging, unpadded [row][32] LDS tiles.
__global__ __launch_bounds__(256) void gemm_kernel(const __bf16* __restrict__ xc,
                                                   const __bf16* __restrict__ wc,
                                                   const float* __restrict__ bias,
                                                   const float* __restrict__ partials,
                                                   float* __restrict__ out) {
    __shared__ float asums[NCH];
    int i0, i1;
    recompute_top2(partials, asums, i0, i1);

    const int c = blockIdx.z;
    const int t = threadIdx.x;
    const size_t obase = (size_t)(blockIdx.x * 128) * NF + c * COUT + blockIdx.y * 128;

    if (c != i0 && c != i1) {
        const float4 z = make_float4(0.f, 0.f, 0.f, 0.f);
        const int rq = t >> 5;             // 0..7
        const int cq = (t & 31) << 2;      // 0..124 step 4
#pragma unroll
        for (int p = 0; p < 16; ++p)
            *(float4*)(out + obase + (size_t)(p * 8 + rq) * NF + cq) = z;
        return;
    }
    const int kz = (c == i0) ? 0 : 1;      // compact chunk id

    __shared__ __bf16 Xs[128 * 32];   // [row][32], UNPADDED (global_load_lds layout)
    __shared__ __bf16 Wsh[128 * 32];

    const int lane = t & 63, w = t >> 6;
    const int wm = (w >> 1) * 64, wn = (w & 1) * 64;   // wave 64x64 sub-tile
    const int lr = lane & 15, lq = lane >> 4;

    // staging: wave w covers rows [w*32, w*32+32) in two 16-row issues
    const int srow = lane >> 2;          // 0..15
    const int skcol = (lane & 3) * 8;    // bf16 k-col within BK
    const __bf16* xg = xc + (size_t)kz * BATCH * CIN
                     + (size_t)(blockIdx.x * 128 + w * 32 + srow) * CIN + skcol;
    const __bf16* wg = wc + (size_t)kz * COUT * CIN
                     + (size_t)(blockIdx.y * 128 + w * 32 + srow) * CIN + skcol;
    __bf16* xls = &Xs[(w * 32) * 32];
    __bf16* wls = &Wsh[(w * 32) * 32];

    f32x4 acc[4][4];
#pragma unroll
    for (int i = 0; i < 4; ++i)
#pragma unroll
        for (int j = 0; j < 4; ++j) acc[i][j] = (f32x4){0.f, 0.f, 0.f, 0.f};

    for (int kk = 0; kk < CIN; kk += 32) {
        async_load16(xg + kk, xls);
        async_load16(xg + kk + (size_t)16 * CIN, xls + 16 * 32);
        async_load16(wg + kk, wls);
        async_load16(wg + kk + (size_t)16 * CIN, wls + 16 * 32);
        __syncthreads();   // drains vmcnt(0): LDS tiles complete

        bf16x8 av[4], bv[4];
#pragma unroll
        for (int mt = 0; mt < 4; ++mt) av[mt] = *(const bf16x8*)&Xs[(wm + mt * 16 + lr) * 32 + lq * 8];
#pragma unroll
        for (int nt = 0; nt < 4; ++nt) bv[nt] = *(const bf16x8*)&Wsh[(wn + nt * 16 + lr) * 32 + lq * 8];
#pragma unroll
        for (int mt = 0; mt < 4; ++mt)
#pragma unroll
            for (int nt = 0; nt < 4; ++nt)
                acc[mt][nt] = __builtin_amdgcn_mfma_f32_16x16x32_bf16(av[mt], bv[nt], acc[mt][nt], 0, 0, 0);
        __syncthreads();
    }

    // ---- epilogue: + bias, store fp32 ----
    float bvv[4];
#pragma unroll
    for (int nt = 0; nt < 4; ++nt)
        bvv[nt] = bias[c * COUT + blockIdx.y * 128 + wn + nt * 16 + lr];
#pragma unroll
    for (int mt = 0; mt < 4; ++mt)
#pragma unroll
        for (int nt = 0; nt < 4; ++nt)
#pragma unroll
            for (int r = 0; r < 4; ++r) {
                const int row = wm + mt * 16 + lq * 4 + r;   // C/D: row = quad*4 + reg
                const int col = wn + nt * 16 + lr;           // C/D: col = lane&15
                out[obase + (size_t)row * NF + col] = acc[mt][nt][r] + bvv[nt];
            }
}

extern "C" void kernel_launch(void* const* d_in, const int* in_sizes, int n_in,
                              void* d_out, int out_size, void* d_ws, size_t ws_size,
                              hipStream_t stream) {
    const float* x = (const float*)d_in[0];
    const float* W = (const float*)d_in[1];
    const float* b = (const float*)d_in[2];
    float* out = (float*)d_out;

    // ws layout: [0, 8K) partials (2048 f32), [32K, +16Mi) xc, then wc (1 MiB)
    float* partials = (float*)d_ws;
    __bf16* xc = (__bf16*)((char*)d_ws + 32768);
    __bf16* wc = (__bf16*)((char*)d_ws + 32768 + (size_t)2 * BATCH * CIN * 2);

    act_kernel<<<dim3(256, NCH), 256, 0, stream>>>(x, partials);
    cvt_kernel<<<dim3(264, 2), 256, 0, stream>>>(x, W, partials, xc, wc,
                                                 out + (size_t)BATCH * NF);
    gemm_kernel<<<dim3(64, 4, NCH), 256, 0, stream>>>(xc, wc, b, partials, out);
}